// Round 10
// baseline (5358.346 us; speedup 1.0000x reference)
//
#include <hip/hip_runtime.h>

// ---------------------------------------------------------------------------
// FractalAttention: B=4, L=4096, D=1024, H=16, DH=64, S=4
//
//  sq_s = x @ (ws[s]@wq).T + (ws[s]@bq + bs[s])   (same for k,v)
//  1. convert x, ws, wo to bf16; transpose wq/wk/wv to bf16
//  2. fuse weights:  Wf[s*3+t] = ws[s] @ w_t   (12x 1024^3, gemm256)
//  3. fuse biases:   bf[s*3+t] = ws[s] @ b_t + bs[s]
//  4. per row-chunk: proj (12 batched) via 256x256 ring-2 GEMM at
//     2 blocks/CU (inter-block pipe overlap: one block's LDS phase runs
//     under the other's MFMA phase — m114/m97 mechanism). Intra-block
//     scheduling levers all failed at 1 block/CU (reg-prefetch +3%,
//     SGB -8%, phase-merge +3%) -> all-scale fused attention (FROZEN)
//  5. single final GEMM: out = comb @ wo.T + bo   (pipelined, f32 out)
// ---------------------------------------------------------------------------

typedef unsigned short u16;
typedef __attribute__((ext_vector_type(8))) short s16x8;
typedef __attribute__((ext_vector_type(8))) unsigned short u16x8;
typedef __attribute__((ext_vector_type(4))) float f32x4;

#define MM 16384        // B*L
#define DDIM 1024
#define DDSQ 1048576ull // D*D

__device__ __forceinline__ u16 f2bf(float f) {
  unsigned u = __float_as_uint(f);
  u = (u + 0x7FFFu + ((u >> 16) & 1u)) >> 16;   // RNE
  return (u16)u;
}
__device__ __forceinline__ float b2f(u16 b) {
  return __uint_as_float(((unsigned)b) << 16);
}
__device__ __forceinline__ void gload_lds16(const void* g, void* l) {
  __builtin_amdgcn_global_load_lds(
      (const __attribute__((address_space(1))) void*)g,
      (__attribute__((address_space(3))) void*)l, 16, 0, 0);
}

// ---------------------------------------------------------------------------
__global__ __launch_bounds__(256) void k_f32_to_bf16(
    const float* __restrict__ in, u16* __restrict__ out, int n4) {
  int i = blockIdx.x * 256 + threadIdx.x;
  if (i >= n4) return;
  float4 v = reinterpret_cast<const float4*>(in)[i];
  ushort4 o;
  o.x = f2bf(v.x); o.y = f2bf(v.y); o.z = f2bf(v.z); o.w = f2bf(v.w);
  reinterpret_cast<ushort4*>(out)[i] = o;
}

// ---------------------------------------------------------------------------
__global__ __launch_bounds__(256) void k_transpose_bf16(
    const float* __restrict__ wq, const float* __restrict__ wk,
    const float* __restrict__ wv, u16* __restrict__ out) {
  __shared__ float tile[32][33];
  const float* src = (blockIdx.z == 0) ? wq : (blockIdx.z == 1) ? wk : wv;
  u16* dst = out + (size_t)blockIdx.z * DDSQ;
  int tx = threadIdx.x, ty = threadIdx.y;
  int bx = blockIdx.x * 32, by = blockIdx.y * 32;
#pragma unroll
  for (int i = 0; i < 4; ++i)
    tile[ty + 8 * i][tx] = src[(size_t)(by + ty + 8 * i) * DDIM + bx + tx];
  __syncthreads();
#pragma unroll
  for (int i = 0; i < 4; ++i)
    dst[(size_t)(bx + ty + 8 * i) * DDIM + by + tx] = f2bf(tile[tx][ty + 8 * i]);
}

// ---------------------------------------------------------------------------
__global__ __launch_bounds__(256) void k_bias_fuse(
    const float* __restrict__ ws, const float* __restrict__ bq,
    const float* __restrict__ bk, const float* __restrict__ bv,
    const float* __restrict__ bs, float* __restrict__ bf) {
  int idx = blockIdx.y;
  int s = idx / 3, t = idx - s * 3;
  const float* bt = (t == 0) ? bq : (t == 1) ? bk : bv;
  int lane = threadIdx.x & 63, wid = threadIdx.x >> 6;
  int e = blockIdx.x * 4 + wid;
  const float* wr = ws + (size_t)s * DDSQ + (size_t)e * DDIM;
  float p = 0.f;
  for (int j = lane; j < DDIM; j += 64) p += wr[j] * bt[j];
#pragma unroll
  for (int off = 32; off > 0; off >>= 1) p += __shfl_xor(p, off);
  if (lane == 0) bf[idx * DDIM + e] = p + bs[s * DDIM + e];
}

// ---------------------------------------------------------------------------
// 256x256 GEMM, ring-2 (64 KB LDS) double-buffer, 2 blocks/CU.
// C = A @ B^T + bias.  BK=32, 512 threads = 8 waves (2m x 4n), per-wave
// 128x64 output.  Per tile: {vmcnt(0) [ring(t) landed, issued mid-tile
// t-1 => ~1 MFMA-phase in flight]; s_barrier; 12 ds_read frags of ring(t);
// STAGE(t+1 -> ring(t+1)); MFMA x32 (compiler-counted lgkm)}.
// Ring safety: barrier at tile t proves all waves retired ring(t+1)&1
// reads (done in tile t-1, lgkm-enforced before their MFMAs).
// Inter-block overlap at 2 blocks/CU supplies the DS<->MFMA pipe overlap
// that intra-block scheduling could not (rounds 5-9).
// XOR swizzle (verified: conflicts = 0) on both write-side global src and
// read-side ds_read addr.  zmode==1: A += (z/3)*za, B += (z%3)*zb.
// ---------------------------------------------------------------------------
template <typename OutT>
__global__ __launch_bounds__(512, 4) void k_gemm256(
    const u16* __restrict__ A, const u16* __restrict__ B, OutT* __restrict__ C,
    const float* __restrict__ bias, int M, int N, int K,
    size_t za, size_t zb, size_t zc, size_t zbias, int nbx, int zmode) {
  __shared__ u16 lds[2][2][8192];   // [ring][A/B][256*32] = 64 KB

  int z = blockIdx.x / nbx;
  int nb = blockIdx.x - z * nbx;
  const u16* Ag; const u16* Bg;
  if (zmode == 1) { Ag = A + (size_t)(z / 3) * za; Bg = B + (size_t)(z % 3) * zb; }
  else            { Ag = A + (size_t)z * za;       Bg = B + (size_t)z * zb; }
  OutT* Cg = C + (size_t)z * zc;
  const float* biasz = bias ? (bias + (size_t)z * zbias) : nullptr;

  int m0 = blockIdx.y * 256, n0 = nb * 256;
  int tid = threadIdx.x;
  int lane = tid & 63, wid = tid >> 6;
  int wm = wid >> 2, wn = wid & 3;          // 2 x 4 waves, 128x64 each
  int NT = K >> 5;                          // K-tiles of 32

  // staging precompute (per-lane global srcs, inverse-swizzled)
  int scb = ((lane & 3) * 16) ^ (((lane >> 3) & 3) << 4);
  const char* srcA[2]; const char* srcB[2]; int ldsc[2];
#pragma unroll
  for (int r = 0; r < 2; ++r) {
    int c = r * 8 + wid;
    int row = c * 16 + (lane >> 2);
    srcA[r] = (const char*)Ag + ((size_t)(m0 + row) * K) * 2 + scb;
    srcB[r] = (const char*)Bg + ((size_t)(n0 + row) * K) * 2 + scb;
    ldsc[r] = c * 1024;
  }
  char* lbase = (char*)&lds[0][0][0];

  // fragment read offsets (swizzled)
  int fxor = ((lane >> 4) * 16) ^ (((lane >> 1) & 3) << 4);
  int aoff = (wm * 128 + (lane & 15)) * 64 + fxor;
  int boff = (wn * 64 + (lane & 15)) * 64 + fxor;

  f32x4 acc[8][4] = {};

#define STAGE_A(kt, rg)                                                   \
  {                                                                       \
    _Pragma("unroll") for (int r = 0; r < 2; ++r)                         \
        gload_lds16(srcA[r] + (size_t)(kt) * 64,                          \
                    lbase + (rg) * 32768 + ldsc[r]);                      \
  }
#define STAGE_B(kt, rg)                                                   \
  {                                                                       \
    _Pragma("unroll") for (int r = 0; r < 2; ++r)                         \
        gload_lds16(srcB[r] + (size_t)(kt) * 64,                          \
                    lbase + (rg) * 32768 + 16384 + ldsc[r]);              \
  }

  // prologue: tile 0 -> ring 0 (4 loads/wave)
  STAGE_A(0, 0); STAGE_B(0, 0);

  for (int t = 0; t < NT; ++t) {
    asm volatile("s_waitcnt vmcnt(0)" ::: "memory");   // ring(t) landed
    asm volatile("s_barrier" ::: "memory");            // all prior reads done
    const char* bA = lbase + (t & 1) * 32768;
    const char* bB = bA + 16384;

    s16x8 fb[4], fa[4], fa2[4];
#pragma unroll
    for (int i = 0; i < 4; ++i)
      fb[i] = *(const s16x8*)(bB + boff + i * 1024);
#pragma unroll
    for (int i = 0; i < 4; ++i)
      fa[i] = *(const s16x8*)(bA + aoff + i * 1024);
#pragma unroll
    for (int i = 0; i < 4; ++i)
      fa2[i] = *(const s16x8*)(bA + aoff + 4096 + i * 1024);

    int ts = (t + 1 < NT) ? t + 1 : t;   // tail: dummy stage keeps ledger
    STAGE_A(ts, (t + 1) & 1); STAGE_B(ts, (t + 1) & 1);

    __builtin_amdgcn_s_setprio(1);
#pragma unroll
    for (int mi = 0; mi < 4; ++mi)
#pragma unroll
      for (int ni = 0; ni < 4; ++ni)
        acc[mi][ni] = __builtin_amdgcn_mfma_f32_16x16x32_bf16(
            fa[mi], fb[ni], acc[mi][ni], 0, 0, 0);
#pragma unroll
    for (int mi = 0; mi < 4; ++mi)
#pragma unroll
      for (int ni = 0; ni < 4; ++ni)
        acc[mi + 4][ni] = __builtin_amdgcn_mfma_f32_16x16x32_bf16(
            fa2[mi], fb[ni], acc[mi + 4][ni], 0, 0, 0);
    __builtin_amdgcn_s_setprio(0);
  }
#undef STAGE_A
#undef STAGE_B

  // drain dummy tail DMAs before LDS can be reallocated to another block
  asm volatile("s_waitcnt vmcnt(0)" ::: "memory");

  // epilogue
#pragma unroll
  for (int mi = 0; mi < 8; ++mi) {
#pragma unroll
    for (int ni = 0; ni < 4; ++ni) {
      int colg = n0 + wn * 64 + ni * 16 + (lane & 15);
      float badd = biasz ? biasz[colg] : 0.f;
#pragma unroll
      for (int r = 0; r < 4; ++r) {
        int rowg = m0 + wm * 128 + mi * 16 + ((lane >> 4) << 2) + r;
        float v = acc[mi][ni][r] + badd;
        if constexpr (sizeof(OutT) == 2) Cg[(size_t)rowg * N + colg] = f2bf(v);
        else                             Cg[(size_t)rowg * N + colg] = v;
      }
    }
  }
}

// ---------------------------------------------------------------------------
// per-position head-mix attention, ALL 4 scales fused. (FROZEN round-5/7
// version: rolled scale loop + per-scale fences. Two unrolled reworks both
// spilled to VGPR 256 / 200+MB scratch — do not unroll this kernel.)
// 256 threads = 4 waves; wave = 1 position.  lane = h*4 + dq.
// ---------------------------------------------------------------------------
__global__ __launch_bounds__(256) void k_attn_all(
    const u16* __restrict__ proj, u16* __restrict__ outbf,
    const float* __restrict__ sl, int rows) {
  __shared__ u16 kv[4][2][1024];   // [wave][K/V][1024]
  int lane = threadIdx.x & 63, wid = threadIdx.x >> 6;
  int row = blockIdx.x * 4 + wid;
  int h = lane >> 2, dq = lane & 3;
  int doff = h * 64 + dq * 16;

  float l0 = sl[0], l1 = sl[1], l2 = sl[2], l3 = sl[3];
  float lm = fmaxf(fmaxf(l0, l1), fmaxf(l2, l3));
  float e0 = __expf(l0 - lm), e1 = __expf(l1 - lm), e2 = __expf(l2 - lm),
        e3 = __expf(l3 - lm);
  float esum = e0 + e1 + e2 + e3;
  float wsc4[4] = {e0 / esum, e1 / esum, e2 / esum, e3 / esum};

  float acc[16];
#pragma unroll
  for (int i = 0; i < 16; ++i) acc[i] = 0.f;

  for (int s = 0; s < 4; ++s) {
    const u16* kr = proj + ((size_t)(3 * s + 1) * rows + row) * DDIM;
    const u16* vr = proj + ((size_t)(3 * s + 2) * rows + row) * DDIM;
    asm volatile("s_waitcnt vmcnt(0) lgkmcnt(0)" ::: "memory");
    gload_lds16(kr + lane * 8,       &kv[wid][0][0]);
    gload_lds16(kr + 512 + lane * 8, &kv[wid][0][512]);
    gload_lds16(vr + lane * 8,       &kv[wid][1][0]);
    gload_lds16(vr + 512 + lane * 8, &kv[wid][1][512]);

    const u16* qr = proj + ((size_t)(3 * s) * rows + row) * DDIM + doff;
    u16x8 q0 = *reinterpret_cast<const u16x8*>(qr);
    u16x8 q1 = *reinterpret_cast<const u16x8*>(qr + 8);
    float qf[16];
#pragma unroll
    for (int i = 0; i < 8; ++i) {
      qf[i]     = b2f(q0[i]) * 0.125f;
      qf[8 + i] = b2f(q1[i]) * 0.125f;
    }
    asm volatile("s_waitcnt vmcnt(0)" ::: "memory");

    float sc[16];
#pragma unroll
    for (int g = 0; g < 16; ++g) {
      const u16* kp = &kv[wid][0][g * 64 + dq * 16];
      u16x8 k0 = *reinterpret_cast<const u16x8*>(kp);
      u16x8 k1 = *reinterpret_cast<const u16x8*>(kp + 8);
      float d = 0.f;
#pragma unroll
      for (int i = 0; i < 8; ++i) d = fmaf(qf[i], b2f(k0[i]), d);
#pragma unroll
      for (int i = 0; i < 8; ++i) d = fmaf(qf[8 + i], b2f(k1[i]), d);
      d += __shfl_xor(d, 1);
      d += __shfl_xor(d, 2);
      sc[g] = d;
    }

    float mx = sc[0];
#pragma unroll
    for (int g = 1; g < 16; ++g) mx = fmaxf(mx, sc[g]);
    float sum = 0.f;
#pragma unroll
    for (int g = 0; g < 16; ++g) { sc[g] = __expf(sc[g] - mx); sum += sc[g]; }
    float inv = wsc4[s] / sum;
#pragma unroll
    for (int g = 0; g < 16; ++g) sc[g] *= inv;

#pragma unroll
    for (int g = 0; g < 16; ++g) {
      float a = sc[g];
      const u16* vp = &kv[wid][1][g * 64 + dq * 16];
      u16x8 v0 = *reinterpret_cast<const u16x8*>(vp);
      u16x8 v1 = *reinterpret_cast<const u16x8*>(vp + 8);
#pragma unroll
      for (int i = 0; i < 8; ++i) {
        acc[i]     = fmaf(a, b2f(v0[i]), acc[i]);
        acc[8 + i] = fmaf(a, b2f(v1[i]), acc[8 + i]);
      }
    }
  }

  u16* op = outbf + (size_t)row * DDIM + doff;
  u16x8 o0, o1;
#pragma unroll
  for (int i = 0; i < 8; ++i) {
    o0[i] = f2bf(acc[i]);
    o1[i] = f2bf(acc[8 + i]);
  }
  *reinterpret_cast<u16x8*>(op) = o0;
  *reinterpret_cast<u16x8*>(op + 8) = o1;
}

// ---------------------------------------------------------------------------
extern "C" void kernel_launch(void* const* d_in, const int* in_sizes, int n_in,
                              void* d_out, int out_size, void* d_ws,
                              size_t ws_size, hipStream_t stream) {
  const float* x  = (const float*)d_in[0];
  const float* sl = (const float*)d_in[1];
  const float* wq = (const float*)d_in[2];
  const float* bq = (const float*)d_in[3];
  const float* wk = (const float*)d_in[4];
  const float* bk = (const float*)d_in[5];
  const float* wv = (const float*)d_in[6];
  const float* bv = (const float*)d_in[7];
  const float* wo = (const float*)d_in[8];
  const float* bo = (const float*)d_in[9];
  const float* ws = (const float*)d_in[10];
  const float* bs = (const float*)d_in[11];
  float* out = (float*)d_out;

  char* wsb = (char*)d_ws;
  size_t off = 0;
  u16* xbf    = (u16*)(wsb + off); off += (size_t)MM * DDIM * 2;   // 32 MB
  u16* wfus   = (u16*)(wsb + off); off += 12ull * DDSQ * 2;        // 24 MB
  u16* wobf   = (u16*)(wsb + off); off += DDSQ * 2;                // 2 MB
  float* bfus = (float*)(wsb + off); off += 65536;                 // 48 KB + pad
  u16* combc  = (u16*)(wsb + off); off += (size_t)MM * DDIM * 2;   // 32 MB
  char* dynr  = wsb + off;
  size_t fixed = off;

  int chunk = 4096;
  while (chunk > 1024 && fixed + (size_t)12 * chunk * DDIM * 2 > ws_size)
    chunk >>= 1;
  u16* projc = (u16*)dynr;
  u16* wtT  = (u16*)dynr;                      // prefuse overlay, 6 MB
  u16* wsbf = (u16*)(dynr + 3ull * DDSQ * 2);  // prefuse overlay, 8 MB

  int n4;
  n4 = MM * DDIM / 4;
  k_f32_to_bf16<<<(n4 + 255) / 256, 256, 0, stream>>>(x, xbf, n4);
  n4 = (int)(4 * DDSQ / 4);
  k_f32_to_bf16<<<(n4 + 255) / 256, 256, 0, stream>>>(ws, wsbf, n4);
  n4 = (int)(DDSQ / 4);
  k_f32_to_bf16<<<(n4 + 255) / 256, 256, 0, stream>>>(wo, wobf, n4);

  k_transpose_bf16<<<dim3(32, 32, 3), dim3(32, 8), 0, stream>>>(wq, wk, wv, wtT);
  k_bias_fuse<<<dim3(256, 12), 256, 0, stream>>>(ws, bq, bk, bv, bs, bfus);

  // fused weights: Wf[s*3+t] = ws_bf[s] @ wtT[t]^T  (zmode=1)
  k_gemm256<u16><<<dim3(48, 4), 512, 0, stream>>>(
      wsbf, wtT, wfus, nullptr, 1024, 1024, 1024, DDSQ, DDSQ, DDSQ, 0, 4, 1);

  // chunked: proj (12 batched, 256^2 ring-2 GEMM) -> fused attention
  int nchunks = MM / chunk;
  for (int c = 0; c < nchunks; ++c) {
    const u16* xa = xbf + (size_t)c * chunk * DDIM;
    k_gemm256<u16><<<dim3(48, chunk / 256), 512, 0, stream>>>(
        xa, wfus, projc, bfus, chunk, 1024, 1024,
        0, DDSQ, (size_t)chunk * DDIM, DDIM, 4, 0);
    k_attn_all<<<dim3(chunk / 4), 256, 0, stream>>>(
        projc, combc + (size_t)c * chunk * DDIM, sl, chunk);
  }

  // single final GEMM: out = comb_bf @ wo^T + bo  (fp32 out)
  k_gemm256<float><<<dim3(4, 64), 512, 0, stream>>>(
      combc, wobf, out, bo, MM, 1024, 1024, 0, 0, 0, 0, 4, 0);
}

// Round 11
// 1014.882 us; speedup vs baseline: 5.2798x; 5.2798x over previous
//
#include <hip/hip_runtime.h>

// ---------------------------------------------------------------------------
// FractalAttention: B=4, L=4096, D=1024, H=16, DH=64, S=4
//
//  sq_s = x @ (ws[s]@wq).T + (ws[s]@bq + bs[s])   (same for k,v)
//  1. convert x, ws, wo to bf16; transpose wq/wk/wv to bf16
//  2. fuse weights:  Wf[s*3+t] = ws[s] @ w_t   (12x 1024^3, m97 GEMM)
//  3. fuse biases:   bf[s*3+t] = ws[s] @ b_t + bs[s]
//  4. per row-chunk: proj (12 batched) via NEW 256x256 GEMM on
//     mfma_f32_32x32x16 (2495 vs 2075 TF pipe), fragment-order LDS for A
//     (conflict-free linear ds_read, no swizzle), B direct global->reg
//     prefetched 1 tile ahead, ring-4 A staging with single counted
//     vmcnt(8)/tile  -> all-scale fused attention (FROZEN rolled version)
//  5. single final GEMM: out = comb @ wo.T + bo  (round-7 gemm256, f32 out)
//
// Round-10 lesson: 2 blocks/CU for a 256^2 tile is impossible (acc=128 VGPR
// > the 128-cap that 4 waves/EU implies) -> launch_bounds(512,2) only.
// ---------------------------------------------------------------------------

typedef unsigned short u16;
typedef __attribute__((ext_vector_type(8))) short s16x8;
typedef __attribute__((ext_vector_type(8))) unsigned short u16x8;
typedef __attribute__((ext_vector_type(4))) float f32x4;
typedef __attribute__((ext_vector_type(16))) float f32x16;

#define MM 16384        // B*L
#define DDIM 1024
#define DDSQ 1048576ull // D*D

__device__ __forceinline__ u16 f2bf(float f) {
  unsigned u = __float_as_uint(f);
  u = (u + 0x7FFFu + ((u >> 16) & 1u)) >> 16;   // RNE
  return (u16)u;
}
__device__ __forceinline__ float b2f(u16 b) {
  return __uint_as_float(((unsigned)b) << 16);
}
__device__ __forceinline__ void gload_lds16(const void* g, void* l) {
  __builtin_amdgcn_global_load_lds(
      (const __attribute__((address_space(1))) void*)g,
      (__attribute__((address_space(3))) void*)l, 16, 0, 0);
}

// ---------------------------------------------------------------------------
__global__ __launch_bounds__(256) void k_f32_to_bf16(
    const float* __restrict__ in, u16* __restrict__ out, int n4) {
  int i = blockIdx.x * 256 + threadIdx.x;
  if (i >= n4) return;
  float4 v = reinterpret_cast<const float4*>(in)[i];
  ushort4 o;
  o.x = f2bf(v.x); o.y = f2bf(v.y); o.z = f2bf(v.z); o.w = f2bf(v.w);
  reinterpret_cast<ushort4*>(out)[i] = o;
}

// ---------------------------------------------------------------------------
__global__ __launch_bounds__(256) void k_transpose_bf16(
    const float* __restrict__ wq, const float* __restrict__ wk,
    const float* __restrict__ wv, u16* __restrict__ out) {
  __shared__ float tile[32][33];
  const float* src = (blockIdx.z == 0) ? wq : (blockIdx.z == 1) ? wk : wv;
  u16* dst = out + (size_t)blockIdx.z * DDSQ;
  int tx = threadIdx.x, ty = threadIdx.y;
  int bx = blockIdx.x * 32, by = blockIdx.y * 32;
#pragma unroll
  for (int i = 0; i < 4; ++i)
    tile[ty + 8 * i][tx] = src[(size_t)(by + ty + 8 * i) * DDIM + bx + tx];
  __syncthreads();
#pragma unroll
  for (int i = 0; i < 4; ++i)
    dst[(size_t)(bx + ty + 8 * i) * DDIM + by + tx] = f2bf(tile[tx][ty + 8 * i]);
}

// ---------------------------------------------------------------------------
__global__ __launch_bounds__(256) void k_bias_fuse(
    const float* __restrict__ ws, const float* __restrict__ bq,
    const float* __restrict__ bk, const float* __restrict__ bv,
    const float* __restrict__ bs, float* __restrict__ bf) {
  int idx = blockIdx.y;
  int s = idx / 3, t = idx - s * 3;
  const float* bt = (t == 0) ? bq : (t == 1) ? bk : bv;
  int lane = threadIdx.x & 63, wid = threadIdx.x >> 6;
  int e = blockIdx.x * 4 + wid;
  const float* wr = ws + (size_t)s * DDSQ + (size_t)e * DDIM;
  float p = 0.f;
  for (int j = lane; j < DDIM; j += 64) p += wr[j] * bt[j];
#pragma unroll
  for (int off = 32; off > 0; off >>= 1) p += __shfl_xor(p, off);
  if (lane == 0) bf[idx * DDIM + e] = p + bs[s * DDIM + e];
}

// ---------------------------------------------------------------------------
// m97-structure GEMM (known good) — weight-fuse only.
// ---------------------------------------------------------------------------
template <typename OutT>
__global__ __launch_bounds__(256) void k_gemm_bt(
    const u16* __restrict__ A, const u16* __restrict__ B, OutT* __restrict__ C,
    const float* __restrict__ bias, int M, int N, int K,
    size_t za, size_t zb, size_t zc, size_t zbias, int zmode) {
  __shared__ u16 lds_a[128 * 32];
  __shared__ u16 lds_b[128 * 32];

  int z = blockIdx.x >> 3;
  int n_blk = blockIdx.x & 7;
  int m_blk = blockIdx.y;
  if (zmode == 1) { A += (size_t)(z / 3) * za; B += (size_t)(z % 3) * zb; }
  else            { A += (size_t)z * za;       B += (size_t)z * zb; }
  C += (size_t)z * zc;
  const float* biasz = bias ? (bias + (size_t)z * zbias) : nullptr;

  int m0 = m_blk * 128, n0 = n_blk * 128;
  int tid = threadIdx.x;
  int lane = tid & 63, wid = tid >> 6;
  int wm = wid >> 1, wn = wid & 1;

  f32x4 acc[4][4] = {};

  auto stage = [&](int k0) {
#pragma unroll
    for (int i = 0; i < 2; ++i) {
      int c = wid * 2 + i;
      int row = c * 16 + (lane >> 2);
      int col = (lane & 3) * 8;
      gload_lds16(A + (size_t)(m0 + row) * K + k0 + col, &lds_a[c * 512]);
      gload_lds16(B + (size_t)(n0 + row) * K + k0 + col, &lds_b[c * 512]);
    }
  };

  stage(0);
  int ar = (wm * 64 + (lane & 15)) * 32 + (lane >> 4) * 8;
  int br = (wn * 64 + (lane & 15)) * 32 + (lane >> 4) * 8;
  for (int k0 = 0;;) {
    __syncthreads();
    s16x8 af[4], bfr[4];
#pragma unroll
    for (int mi = 0; mi < 4; ++mi)
      af[mi] = *reinterpret_cast<const s16x8*>(&lds_a[ar + mi * 16 * 32]);
#pragma unroll
    for (int ni = 0; ni < 4; ++ni)
      bfr[ni] = *reinterpret_cast<const s16x8*>(&lds_b[br + ni * 16 * 32]);
#pragma unroll
    for (int mi = 0; mi < 4; ++mi)
#pragma unroll
      for (int ni = 0; ni < 4; ++ni)
        acc[mi][ni] = __builtin_amdgcn_mfma_f32_16x16x32_bf16(
            af[mi], bfr[ni], acc[mi][ni], 0, 0, 0);
    k0 += 32;
    if (k0 >= K) break;
    __syncthreads();
    stage(k0);
  }

#pragma unroll
  for (int mi = 0; mi < 4; ++mi) {
#pragma unroll
    for (int ni = 0; ni < 4; ++ni) {
      int colg = n0 + wn * 64 + ni * 16 + (lane & 15);
      float badd = biasz ? biasz[colg] : 0.f;
#pragma unroll
      for (int r = 0; r < 4; ++r) {
        int rowg = m0 + wm * 64 + mi * 16 + ((lane >> 4) << 2) + r;
        float v = acc[mi][ni][r] + badd;
        if constexpr (sizeof(OutT) == 2) C[(size_t)rowg * N + colg] = f2bf(v);
        else                             C[(size_t)rowg * N + colg] = v;
      }
    }
  }
}

// ---------------------------------------------------------------------------
// Round-7 256x256 pipelined GEMM (16x16 MFMA, ring-4, reg-dbuf ds_reads).
// Known good: 105.5us proj-class. Used for the FINAL GEMM only.
// ---------------------------------------------------------------------------
template <typename OutT>
__global__ __launch_bounds__(512, 1) void k_gemm256(
    const u16* __restrict__ A, const u16* __restrict__ B, OutT* __restrict__ C,
    const float* __restrict__ bias, int M, int N, int K,
    size_t za, size_t zb, size_t zc, size_t zbias, int nbx) {
  __shared__ u16 lds[4][2][8192];   // [ring][A/B][256*32]

  int z = blockIdx.x / nbx;
  int nb = blockIdx.x - z * nbx;
  const u16* Ag = A + (size_t)z * za;
  const u16* Bg = B + (size_t)z * zb;
  OutT* Cg = C + (size_t)z * zc;
  const float* biasz = bias + (size_t)z * zbias;

  int m0 = blockIdx.y * 256, n0 = nb * 256;
  int tid = threadIdx.x;
  int lane = tid & 63, wid = tid >> 6;
  int wm = wid >> 2, wn = wid & 3;
  int NT = K >> 5;

  int scb = ((lane & 3) * 16) ^ (((lane >> 3) & 3) << 4);
  const char* srcA[2]; const char* srcB[2]; int ldsc[2];
#pragma unroll
  for (int r = 0; r < 2; ++r) {
    int c = r * 8 + wid;
    int row = c * 16 + (lane >> 2);
    srcA[r] = (const char*)Ag + ((size_t)(m0 + row) * K) * 2 + scb;
    srcB[r] = (const char*)Bg + ((size_t)(n0 + row) * K) * 2 + scb;
    ldsc[r] = c * 1024;
  }
  char* lbase = (char*)&lds[0][0][0];

  int fxor = ((lane >> 4) * 16) ^ (((lane >> 1) & 3) << 4);
  int aoff = (wm * 128 + (lane & 15)) * 64 + fxor;
  int boff = (wn * 64 + (lane & 15)) * 64 + fxor;

  f32x4 acc[8][4] = {};
  s16x8 cA0[4], cA1[4], cB[4];
  s16x8 nA0[4], nA1[4], nB[4];

#define STAGE_A(kt, rg)                                                   \
  {                                                                       \
    _Pragma("unroll") for (int r = 0; r < 2; ++r)                         \
        gload_lds16(srcA[r] + (size_t)(kt) * 64,                          \
                    lbase + (rg) * 32768 + ldsc[r]);                      \
  }
#define STAGE_B(kt, rg)                                                   \
  {                                                                       \
    _Pragma("unroll") for (int r = 0; r < 2; ++r)                         \
        gload_lds16(srcB[r] + (size_t)(kt) * 64,                          \
                    lbase + (rg) * 32768 + 16384 + ldsc[r]);              \
  }
#define SUBITER(C0, C1, CBv, N0, N1, NBv, tcur)                           \
  {                                                                       \
    asm volatile("s_waitcnt vmcnt(4)" ::: "memory");                      \
    asm volatile("s_barrier" ::: "memory");                               \
    int tn = (tcur) + 1 < NT ? (tcur) + 1 : NT - 1;                       \
    const char* bA = lbase + (tn & 3) * 32768;                            \
    const char* bB = bA + 16384;                                          \
    _Pragma("unroll") for (int i = 0; i < 4; ++i)                         \
        NBv[i] = *(const s16x8*)(bB + boff + i * 1024);                   \
    _Pragma("unroll") for (int i = 0; i < 4; ++i)                         \
        N0[i] = *(const s16x8*)(bA + aoff + i * 1024);                    \
    _Pragma("unroll") for (int i = 0; i < 4; ++i)                         \
        N1[i] = *(const s16x8*)(bA + aoff + 4096 + i * 1024);             \
    int ts = (tcur) + 3 < NT ? (tcur) + 3 : NT - 1;                       \
    int rgs = ((tcur) + 3) & 3;                                           \
    STAGE_A(ts, rgs); STAGE_B(ts, rgs);                                   \
    __builtin_amdgcn_s_setprio(1);                                        \
    _Pragma("unroll") for (int mi = 0; mi < 4; ++mi)                      \
      _Pragma("unroll") for (int ni = 0; ni < 4; ++ni)                    \
          acc[mi][ni] = __builtin_amdgcn_mfma_f32_16x16x32_bf16(          \
              C0[mi], CBv[ni], acc[mi][ni], 0, 0, 0);                     \
    _Pragma("unroll") for (int mi = 0; mi < 4; ++mi)                      \
      _Pragma("unroll") for (int ni = 0; ni < 4; ++ni)                    \
          acc[mi + 4][ni] = __builtin_amdgcn_mfma_f32_16x16x32_bf16(      \
              C1[mi], CBv[ni], acc[mi + 4][ni], 0, 0, 0);                 \
    __builtin_amdgcn_s_setprio(0);                                        \
  }

  STAGE_A(0, 0); STAGE_B(0, 0);
  STAGE_A(1, 1); STAGE_B(1, 1);
  STAGE_A(2, 2); STAGE_B(2, 2);
  asm volatile("s_waitcnt vmcnt(8)" ::: "memory");
  asm volatile("s_barrier" ::: "memory");
  {
    const char* bA = lbase;
    const char* bB = bA + 16384;
#pragma unroll
    for (int i = 0; i < 4; ++i) cB[i]  = *(const s16x8*)(bB + boff + i * 1024);
#pragma unroll
    for (int i = 0; i < 4; ++i) cA0[i] = *(const s16x8*)(bA + aoff + i * 1024);
#pragma unroll
    for (int i = 0; i < 4; ++i)
      cA1[i] = *(const s16x8*)(bA + aoff + 4096 + i * 1024);
  }

  for (int t = 0; t < NT; t += 2) {
    SUBITER(cA0, cA1, cB, nA0, nA1, nB, t);
    SUBITER(nA0, nA1, nB, cA0, cA1, cB, t + 1);
  }
#undef SUBITER
#undef STAGE_A
#undef STAGE_B

  asm volatile("s_waitcnt vmcnt(0)" ::: "memory");

#pragma unroll
  for (int mi = 0; mi < 8; ++mi) {
#pragma unroll
    for (int ni = 0; ni < 4; ++ni) {
      int colg = n0 + wn * 64 + ni * 16 + (lane & 15);
      float badd = biasz[colg];
#pragma unroll
      for (int r = 0; r < 4; ++r) {
        int rowg = m0 + wm * 128 + mi * 16 + ((lane >> 4) << 2) + r;
        float v = acc[mi][ni][r] + badd;
        if constexpr (sizeof(OutT) == 2) Cg[(size_t)rowg * N + colg] = f2bf(v);
        else                             Cg[(size_t)rowg * N + colg] = v;
      }
    }
  }
}

// ---------------------------------------------------------------------------
// NEW proj GEMM: 256x256 tile on mfma_f32_32x32x16_bf16 (2495 TF pipe).
// 512 thr = 8 waves (2m x 4n), wave tile 128x64: 4 m-frags x 2 n-frags of
// 32x32, acc = 8 x f32x16 = 128 VGPR.  BK=32, NT=K/32 (even).
//
// A: fragment-order LDS. One 1KB chunk per (32-row-block mb, kk): lane l's
// 16B = A[m0+mb*32+(l&31)][k: kt*32+kk*16+(l>>5)*8 ..+8].  global_load_lds
// writes base+lane*16 (linear); the per-lane GLOBAL src does the gather.
// Consumer ds_read_b128 at chunk_base+lane*16 -> contiguous 1KB, conflict-
// free by construction (no swizzle).  Ring-4 (64KB), distance-3 staging,
// single manual vmcnt(8) per tile (A-ring only; never 0 in loop).
// B: direct global->VGPR, lane l = B^T[n0+wn*64+nf*32+(l&31)][same k],
// prefetched 1 tile ahead into named regsets (compiler-counted waits).
// C/D layout (m74/m101): col=lane&31, row=(reg&3)+8*(reg>>2)+4*(lane>>5).
// ---------------------------------------------------------------------------
__global__ __launch_bounds__(512, 2) void k_gemm32(
    const u16* __restrict__ A, const u16* __restrict__ B, u16* __restrict__ C,
    const float* __restrict__ bias, int M, int N, int K,
    size_t za, size_t zb, size_t zc, size_t zbias, int nbx) {
  __shared__ char lds[4 * 16384];   // 4 rings x (256x32 bf16 A) = 64 KB

  int z = blockIdx.x / nbx;
  int nb = blockIdx.x - z * nbx;
  const u16* Ag = A + (size_t)z * za;
  const u16* Bg = B + (size_t)z * zb;
  u16* Cg = C + (size_t)z * zc;
  const float* biasz = bias + (size_t)z * zbias;

  int m0 = blockIdx.y * 256, n0 = nb * 256;
  int tid = threadIdx.x;
  int lane = tid & 63, wid = tid >> 6;
  int wm = wid >> 2, wn = wid & 3;          // 2 x 4 waves, 128x64 each
  int NT = K >> 5;                          // K-tiles of 32 (even)
  int lrow = lane & 31, lhalf = lane >> 5;  // frag row / k-half

  // A staging sources: wave wid stages mb=wid's two kk chunks.
  const char* srcA[2];
#pragma unroll
  for (int i = 0; i < 2; ++i)
    srcA[i] = (const char*)Ag +
              ((size_t)(m0 + wid * 32 + lrow) * K + i * 16 + lhalf * 8) * 2;

  // B per-lane global pointers (per n-frag); advance t*64 + kk*32 bytes.
  const char* pB[2];
#pragma unroll
  for (int nf = 0; nf < 2; ++nf)
    pB[nf] = (const char*)Bg +
             ((size_t)(n0 + wn * 64 + nf * 32 + lrow) * K + lhalf * 8) * 2;

  char* lb = lds;
  int lane16 = lane * 16;

  f32x16 acc[4][2] = {};
  s16x8 cBf[2][2], nBf[2][2];   // [nf][kk], current / next tile

#define STAGE_A(kt, rg)                                                   \
  {                                                                       \
    _Pragma("unroll") for (int i = 0; i < 2; ++i)                         \
        gload_lds16(srcA[i] + (size_t)(kt) * 64,                          \
                    lb + (rg) * 16384 + (wid * 2 + i) * 1024);            \
  }

#define SUBITER(CB_, NB_, tcur)                                           \
  {                                                                        \
    asm volatile("s_waitcnt vmcnt(8)" ::: "memory");  /* ring(t) landed */ \
    asm volatile("s_barrier" ::: "memory");                                \
    const char* bA = lb + ((tcur) & 3) * 16384;                            \
    s16x8 fa[4][2];                                                        \
    _Pragma("unroll") for (int mf = 0; mf < 4; ++mf)                       \
      _Pragma("unroll") for (int kk = 0; kk < 2; ++kk)                     \
          fa[mf][kk] = *(const s16x8*)(bA +                                \
              ((wm * 4 + mf) * 2 + kk) * 1024 + lane16);                   \
    int tn = (tcur) + 1 < NT ? (tcur) + 1 : NT - 1;                        \
    _Pragma("unroll") for (int nf = 0; nf < 2; ++nf)                       \
      _Pragma("unroll") for (int kk = 0; kk < 2; ++kk)                     \
          NB_[nf][kk] = *(const s16x8*)(pB[nf] +                           \
              (size_t)tn * 64 + kk * 32);                                  \
    int ts = (tcur) + 3 < NT ? (tcur) + 3 : NT - 1;                        \
    STAGE_A(ts, ((tcur) + 3) & 3);                                         \
    __builtin_amdgcn_s_setprio(1);                                         \
    _Pragma("unroll") for (int mf = 0; mf < 4; ++mf)                       \
      _Pragma("unroll") for (int nf = 0; nf < 2; ++nf)                     \
        _Pragma("unroll") for (int kk = 0; kk < 2; ++kk)                   \
            acc[mf][nf] = __builtin_amdgcn_mfma_f32_32x32x16_bf16(         \
                fa[mf][kk], CB_[nf][kk], acc[mf][nf], 0, 0, 0);            \
    __builtin_amdgcn_s_setprio(0);                                         \
  }

  // prologue: A tiles 0,1,2 -> rings 0,1,2 (6 gloads); B(0) -> cBf
  STAGE_A(0, 0);
  STAGE_A(1, 1);
  STAGE_A(2, 2);
#pragma unroll
  for (int nf = 0; nf < 2; ++nf)
#pragma unroll
    for (int kk = 0; kk < 2; ++kk)
      cBf[nf][kk] = *(const s16x8*)(pB[nf] + kk * 32);

  for (int t = 0; t < NT; t += 2) {
    SUBITER(cBf, nBf, t);
    SUBITER(nBf, cBf, t + 1);
  }
#undef SUBITER
#undef STAGE_A

  // drain dummy tail DMAs before LDS can be reallocated
  asm volatile("s_waitcnt vmcnt(0)" ::: "memory");

  // epilogue: 32x32 C/D layout
#pragma unroll
  for (int mf = 0; mf < 4; ++mf) {
#pragma unroll
    for (int nf = 0; nf < 2; ++nf) {
      int colg = n0 + wn * 64 + nf * 32 + lrow;
      float badd = biasz[colg];
#pragma unroll
      for (int reg = 0; reg < 16; ++reg) {
        int rowf = (reg & 3) + 8 * (reg >> 2) + 4 * lhalf;
        int rowg = m0 + wm * 128 + mf * 32 + rowf;
        Cg[(size_t)rowg * N + colg] = f2bf(acc[mf][nf][reg] + badd);
      }
    }
  }
}

// ---------------------------------------------------------------------------
// per-position head-mix attention, ALL 4 scales fused. (FROZEN round-5/7
// version: rolled scale loop + per-scale fences. Do not unroll — two
// unrolled variants spilled to VGPR 256 / 200+MB scratch.)
// ---------------------------------------------------------------------------
__global__ __launch_bounds__(256) void k_attn_all(
    const u16* __restrict__ proj, u16* __restrict__ outbf,
    const float* __restrict__ sl, int rows) {
  __shared__ u16 kv[4][2][1024];   // [wave][K/V][1024]
  int lane = threadIdx.x & 63, wid = threadIdx.x >> 6;
  int row = blockIdx.x * 4 + wid;
  int h = lane >> 2, dq = lane & 3;
  int doff = h * 64 + dq * 16;

  float l0 = sl[0], l1 = sl[1], l2 = sl[2], l3 = sl[3];
  float lm = fmaxf(fmaxf(l0, l1), fmaxf(l2, l3));
  float e0 = __expf(l0 - lm), e1 = __expf(l1 - lm), e2 = __expf(l2 - lm),
        e3 = __expf(l3 - lm);
  float esum = e0 + e1 + e2 + e3;
  float wsc4[4] = {e0 / esum, e1 / esum, e2 / esum, e3 / esum};

  float acc[16];
#pragma unroll
  for (int i = 0; i < 16; ++i) acc[i] = 0.f;

  for (int s = 0; s < 4; ++s) {
    const u16* kr = proj + ((size_t)(3 * s + 1) * rows + row) * DDIM;
    const u16* vr = proj + ((size_t)(3 * s + 2) * rows + row) * DDIM;
    asm volatile("s_waitcnt vmcnt(0) lgkmcnt(0)" ::: "memory");
    gload_lds16(kr + lane * 8,       &kv[wid][0][0]);
    gload_lds16(kr + 512 + lane * 8, &kv[wid][0][512]);
    gload_lds16(vr + lane * 8,       &kv[wid][1][0]);
    gload_lds16(vr + 512 + lane * 8, &kv[wid][1][512]);

    const u16* qr = proj + ((size_t)(3 * s) * rows + row) * DDIM + doff;
    u16x8 q0 = *reinterpret_cast<const u16x8*>(qr);
    u16x8 q1 = *reinterpret_cast<const u16x8*>(qr + 8);
    float qf[16];
#pragma unroll
    for (int i = 0; i < 8; ++i) {
      qf[i]     = b2f(q0[i]) * 0.125f;
      qf[8 + i] = b2f(q1[i]) * 0.125f;
    }
    asm volatile("s_waitcnt vmcnt(0)" ::: "memory");

    float sc[16];
#pragma unroll
    for (int g = 0; g < 16; ++g) {
      const u16* kp = &kv[wid][0][g * 64 + dq * 16];
      u16x8 k0 = *reinterpret_cast<const u16x8*>(kp);
      u16x8 k1 = *reinterpret_cast<const u16x8*>(kp + 8);
      float d = 0.f;
#pragma unroll
      for (int i = 0; i < 8; ++i) d = fmaf(qf[i], b2f(k0[i]), d);
#pragma unroll
      for (int i = 0; i < 8; ++i) d = fmaf(qf[8 + i], b2f(k1[i]), d);
      d += __shfl_xor(d, 1);
      d += __shfl_xor(d, 2);
      sc[g] = d;
    }

    float mx = sc[0];
#pragma unroll
    for (int g = 1; g < 16; ++g) mx = fmaxf(mx, sc[g]);
    float sum = 0.f;
#pragma unroll
    for (int g = 0; g < 16; ++g) { sc[g] = __expf(sc[g] - mx); sum += sc[g]; }
    float inv = wsc4[s] / sum;
#pragma unroll
    for (int g = 0; g < 16; ++g) sc[g] *= inv;

#pragma unroll
    for (int g = 0; g < 16; ++g) {
      float a = sc[g];
      const u16* vp = &kv[wid][1][g * 64 + dq * 16];
      u16x8 v0 = *reinterpret_cast<const u16x8*>(vp);
      u16x8 v1 = *reinterpret_cast<const u16x8*>(vp + 8);
#pragma unroll
      for (int i = 0; i < 8; ++i) {
        acc[i]     = fmaf(a, b2f(v0[i]), acc[i]);
        acc[8 + i] = fmaf(a, b2f(v1[i]), acc[8 + i]);
      }
    }
  }

  u16* op = outbf + (size_t)row * DDIM + doff;
  u16x8 o0, o1;
#pragma unroll
  for (int i = 0; i < 8; ++i) {
    o0[i] = f2bf(acc[i]);
    o1[i] = f2bf(acc[8 + i]);
  }
  *reinterpret_cast<u16x8*>(op) = o0;
  *reinterpret_cast<u16x8*>(op + 8) = o1;
}

// ---------------------------------------------------------------------------
extern "C" void kernel_launch(void* const* d_in, const int* in_sizes, int n_in,
                              void* d_out, int out_size, void* d_ws,
                              size_t ws_size, hipStream_t stream) {
  const float* x  = (const float*)d_in[0];
  const float* sl = (const float*)d_in[1];
  const float* wq = (const float*)d_in[2];
  const float* bq = (const float*)d_in[3];
  const float* wk = (const float*)d_in[4];
  const float* bk = (const float*)d_in[5];
  const float* wv = (const float*)d_in[6];
  const float* bv = (const float*)d_in[7];
  const float* wo = (const float*)d_in[8];
  const float* bo = (const float*)d_in[9];
  const float* ws = (const float*)d_in[10];
  const float* bs = (const float*)d_in[11];
  float* out = (float*)d_out;

  char* wsb = (char*)d_ws;
  size_t off = 0;
  u16* xbf    = (u16*)(wsb + off); off += (size_t)MM * DDIM * 2;   // 32 MB
  u16* wfus   = (u16*)(wsb + off); off += 12ull * DDSQ * 2;        // 24 MB
  u16* wobf   = (u16*)(wsb + off); off += DDSQ * 2;                // 2 MB
  float* bfus = (float*)(wsb + off); off += 65536;                 // 48 KB + pad
  u16* combc  = (u16*)(wsb + off); off += (size_t)MM * DDIM * 2;   // 32 MB
  char* dynr  = wsb + off;
  size_t fixed = off;

  int chunk = 4096;
  while (chunk > 1024 && fixed + (size_t)12 * chunk * DDIM * 2 > ws_size)
    chunk >>= 1;
  u16* projc = (u16*)dynr;
  u16* wtT  = (u16*)dynr;                      // prefuse overlay, 6 MB
  u16* wsbf = (u16*)(dynr + 3ull * DDSQ * 2);  // prefuse overlay, 8 MB

  int n4;
  n4 = MM * DDIM / 4;
  k_f32_to_bf16<<<(n4 + 255) / 256, 256, 0, stream>>>(x, xbf, n4);
  n4 = (int)(4 * DDSQ / 4);
  k_f32_to_bf16<<<(n4 + 255) / 256, 256, 0, stream>>>(ws, wsbf, n4);
  n4 = (int)(DDSQ / 4);
  k_f32_to_bf16<<<(n4 + 255) / 256, 256, 0, stream>>>(wo, wobf, n4);

  k_transpose_bf16<<<dim3(32, 32, 3), dim3(32, 8), 0, stream>>>(wq, wk, wv, wtT);
  k_bias_fuse<<<dim3(256, 12), 256, 0, stream>>>(ws, bq, bk, bv, bs, bfus);

  // fused weights (m97 kernel, known good)
  k_gemm_bt<u16><<<dim3(96, 8), 256, 0, stream>>>(
      wsbf, wtT, wfus, nullptr, 1024, 1024, 1024, DDSQ, DDSQ, DDSQ, 0, 1);

  // chunked: proj (12 batched, NEW 32x32-MFMA GEMM) -> fused attention
  int nchunks = MM / chunk;
  for (int c = 0; c < nchunks; ++c) {
    const u16* xa = xbf + (size_t)c * chunk * DDIM;
    k_gemm32<<<dim3(48, chunk / 256), 512, 0, stream>>>(
        xa, wfus, projc, bfus, chunk, 1024, 1024,
        0, DDSQ, (size_t)chunk * DDIM, DDIM, 4);
    k_attn_all<<<dim3(chunk / 4), 256, 0, stream>>>(
        projc, combc + (size_t)c * chunk * DDIM, sl, chunk);
  }

  // single final GEMM (round-7 kernel): out = comb_bf @ wo^T + bo
  k_gemm256<float><<<dim3(4, 64), 512, 0, stream>>>(
      combc, wobf, out, bo, MM, 1024, 1024, 0, 0, 0, 0, 4);
}

// Round 12
// 690.041 us; speedup vs baseline: 7.7653x; 1.4708x over previous
//
#include <hip/hip_runtime.h>

// ---------------------------------------------------------------------------
// FractalAttention: B=4, L=4096, D=1024, H=16, DH=64, S=4
//
//  sq_s = x @ (ws[s]@wq).T + (ws[s]@bq + bs[s])   (same for k,v)
//  1. convert x, ws, wo to bf16; transpose wq/wk/wv to bf16
//  2. fuse weights:  Wf[s*3+t] = ws[s] @ w_t   (12x 1024^3, m97 GEMM)
//  3. fuse biases:   bf[s*3+t] = ws[s] @ b_t + bs[s]
//  4. per row-chunk: proj (12 batched, round-7 256^2 ring-4 reg-dbuf GEMM)
//     -> all-scale fused attention (rolled loop + LDS K/V double-buffer;
//        DMA for scale s+1 issued under compute of scale s, vmcnt(6))
//  5. single final GEMM: out = comb @ wo.T + bo  (round-7 gemm256, f32 out)
//
// GEMM experiment ledger (do not retry): SGB interleave -8% (r9);
// 2 blocks/CU for 256^2 impossible (acc=128 VGPR, r10); per-lane gathered
// global loads serialize the TA ~2000cyc/tile (r11); unrolled attn scale
// loop spills to 256 VGPR (r6, r8).
// ---------------------------------------------------------------------------

typedef unsigned short u16;
typedef __attribute__((ext_vector_type(8))) short s16x8;
typedef __attribute__((ext_vector_type(8))) unsigned short u16x8;
typedef __attribute__((ext_vector_type(4))) float f32x4;

#define MM 16384        // B*L
#define DDIM 1024
#define DDSQ 1048576ull // D*D

__device__ __forceinline__ u16 f2bf(float f) {
  unsigned u = __float_as_uint(f);
  u = (u + 0x7FFFu + ((u >> 16) & 1u)) >> 16;   // RNE
  return (u16)u;
}
__device__ __forceinline__ float b2f(u16 b) {
  return __uint_as_float(((unsigned)b) << 16);
}
__device__ __forceinline__ void gload_lds16(const void* g, void* l) {
  __builtin_amdgcn_global_load_lds(
      (const __attribute__((address_space(1))) void*)g,
      (__attribute__((address_space(3))) void*)l, 16, 0, 0);
}

// ---------------------------------------------------------------------------
__global__ __launch_bounds__(256) void k_f32_to_bf16(
    const float* __restrict__ in, u16* __restrict__ out, int n4) {
  int i = blockIdx.x * 256 + threadIdx.x;
  if (i >= n4) return;
  float4 v = reinterpret_cast<const float4*>(in)[i];
  ushort4 o;
  o.x = f2bf(v.x); o.y = f2bf(v.y); o.z = f2bf(v.z); o.w = f2bf(v.w);
  reinterpret_cast<ushort4*>(out)[i] = o;
}

// ---------------------------------------------------------------------------
__global__ __launch_bounds__(256) void k_transpose_bf16(
    const float* __restrict__ wq, const float* __restrict__ wk,
    const float* __restrict__ wv, u16* __restrict__ out) {
  __shared__ float tile[32][33];
  const float* src = (blockIdx.z == 0) ? wq : (blockIdx.z == 1) ? wk : wv;
  u16* dst = out + (size_t)blockIdx.z * DDSQ;
  int tx = threadIdx.x, ty = threadIdx.y;
  int bx = blockIdx.x * 32, by = blockIdx.y * 32;
#pragma unroll
  for (int i = 0; i < 4; ++i)
    tile[ty + 8 * i][tx] = src[(size_t)(by + ty + 8 * i) * DDIM + bx + tx];
  __syncthreads();
#pragma unroll
  for (int i = 0; i < 4; ++i)
    dst[(size_t)(bx + ty + 8 * i) * DDIM + by + tx] = f2bf(tile[tx][ty + 8 * i]);
}

// ---------------------------------------------------------------------------
__global__ __launch_bounds__(256) void k_bias_fuse(
    const float* __restrict__ ws, const float* __restrict__ bq,
    const float* __restrict__ bk, const float* __restrict__ bv,
    const float* __restrict__ bs, float* __restrict__ bf) {
  int idx = blockIdx.y;
  int s = idx / 3, t = idx - s * 3;
  const float* bt = (t == 0) ? bq : (t == 1) ? bk : bv;
  int lane = threadIdx.x & 63, wid = threadIdx.x >> 6;
  int e = blockIdx.x * 4 + wid;
  const float* wr = ws + (size_t)s * DDSQ + (size_t)e * DDIM;
  float p = 0.f;
  for (int j = lane; j < DDIM; j += 64) p += wr[j] * bt[j];
#pragma unroll
  for (int off = 32; off > 0; off >>= 1) p += __shfl_xor(p, off);
  if (lane == 0) bf[idx * DDIM + e] = p + bs[s * DDIM + e];
}

// ---------------------------------------------------------------------------
// m97-structure GEMM (known good) — weight-fuse only.
// ---------------------------------------------------------------------------
template <typename OutT>
__global__ __launch_bounds__(256) void k_gemm_bt(
    const u16* __restrict__ A, const u16* __restrict__ B, OutT* __restrict__ C,
    const float* __restrict__ bias, int M, int N, int K,
    size_t za, size_t zb, size_t zc, size_t zbias, int zmode) {
  __shared__ u16 lds_a[128 * 32];
  __shared__ u16 lds_b[128 * 32];

  int z = blockIdx.x >> 3;
  int n_blk = blockIdx.x & 7;
  int m_blk = blockIdx.y;
  if (zmode == 1) { A += (size_t)(z / 3) * za; B += (size_t)(z % 3) * zb; }
  else            { A += (size_t)z * za;       B += (size_t)z * zb; }
  C += (size_t)z * zc;
  const float* biasz = bias ? (bias + (size_t)z * zbias) : nullptr;

  int m0 = m_blk * 128, n0 = n_blk * 128;
  int tid = threadIdx.x;
  int lane = tid & 63, wid = tid >> 6;
  int wm = wid >> 1, wn = wid & 1;

  f32x4 acc[4][4] = {};

  auto stage = [&](int k0) {
#pragma unroll
    for (int i = 0; i < 2; ++i) {
      int c = wid * 2 + i;
      int row = c * 16 + (lane >> 2);
      int col = (lane & 3) * 8;
      gload_lds16(A + (size_t)(m0 + row) * K + k0 + col, &lds_a[c * 512]);
      gload_lds16(B + (size_t)(n0 + row) * K + k0 + col, &lds_b[c * 512]);
    }
  };

  stage(0);
  int ar = (wm * 64 + (lane & 15)) * 32 + (lane >> 4) * 8;
  int br = (wn * 64 + (lane & 15)) * 32 + (lane >> 4) * 8;
  for (int k0 = 0;;) {
    __syncthreads();
    s16x8 af[4], bfr[4];
#pragma unroll
    for (int mi = 0; mi < 4; ++mi)
      af[mi] = *reinterpret_cast<const s16x8*>(&lds_a[ar + mi * 16 * 32]);
#pragma unroll
    for (int ni = 0; ni < 4; ++ni)
      bfr[ni] = *reinterpret_cast<const s16x8*>(&lds_b[br + ni * 16 * 32]);
#pragma unroll
    for (int mi = 0; mi < 4; ++mi)
#pragma unroll
      for (int ni = 0; ni < 4; ++ni)
        acc[mi][ni] = __builtin_amdgcn_mfma_f32_16x16x32_bf16(
            af[mi], bfr[ni], acc[mi][ni], 0, 0, 0);
    k0 += 32;
    if (k0 >= K) break;
    __syncthreads();
    stage(k0);
  }

#pragma unroll
  for (int mi = 0; mi < 4; ++mi) {
#pragma unroll
    for (int ni = 0; ni < 4; ++ni) {
      int colg = n0 + wn * 64 + ni * 16 + (lane & 15);
      float badd = biasz ? biasz[colg] : 0.f;
#pragma unroll
      for (int r = 0; r < 4; ++r) {
        int rowg = m0 + wm * 64 + mi * 16 + ((lane >> 4) << 2) + r;
        float v = acc[mi][ni][r] + badd;
        if constexpr (sizeof(OutT) == 2) C[(size_t)rowg * N + colg] = f2bf(v);
        else                             C[(size_t)rowg * N + colg] = v;
      }
    }
  }
}

// ---------------------------------------------------------------------------
// Round-7 256x256 pipelined GEMM (16x16 MFMA, ring-4, reg-dbuf ds_reads).
// Known good: 105.5us proj-class, MfmaUtil 43%, conflicts 0. Proj + final.
// ---------------------------------------------------------------------------
template <typename OutT>
__global__ __launch_bounds__(512, 1) void k_gemm256(
    const u16* __restrict__ A, const u16* __restrict__ B, OutT* __restrict__ C,
    const float* __restrict__ bias, int M, int N, int K,
    size_t za, size_t zb, size_t zc, size_t zbias, int nbx) {
  __shared__ u16 lds[4][2][8192];   // [ring][A/B][256*32]

  int z = blockIdx.x / nbx;
  int nb = blockIdx.x - z * nbx;
  const u16* Ag = A + (size_t)z * za;
  const u16* Bg = B + (size_t)z * zb;
  OutT* Cg = C + (size_t)z * zc;
  const float* biasz = bias + (size_t)z * zbias;

  int m0 = blockIdx.y * 256, n0 = nb * 256;
  int tid = threadIdx.x;
  int lane = tid & 63, wid = tid >> 6;
  int wm = wid >> 2, wn = wid & 3;
  int NT = K >> 5;

  int scb = ((lane & 3) * 16) ^ (((lane >> 3) & 3) << 4);
  const char* srcA[2]; const char* srcB[2]; int ldsc[2];
#pragma unroll
  for (int r = 0; r < 2; ++r) {
    int c = r * 8 + wid;
    int row = c * 16 + (lane >> 2);
    srcA[r] = (const char*)Ag + ((size_t)(m0 + row) * K) * 2 + scb;
    srcB[r] = (const char*)Bg + ((size_t)(n0 + row) * K) * 2 + scb;
    ldsc[r] = c * 1024;
  }
  char* lbase = (char*)&lds[0][0][0];

  int fxor = ((lane >> 4) * 16) ^ (((lane >> 1) & 3) << 4);
  int aoff = (wm * 128 + (lane & 15)) * 64 + fxor;
  int boff = (wn * 64 + (lane & 15)) * 64 + fxor;

  f32x4 acc[8][4] = {};
  s16x8 cA0[4], cA1[4], cB[4];
  s16x8 nA0[4], nA1[4], nB[4];

#define STAGE_A(kt, rg)                                                   \
  {                                                                       \
    _Pragma("unroll") for (int r = 0; r < 2; ++r)                         \
        gload_lds16(srcA[r] + (size_t)(kt) * 64,                          \
                    lbase + (rg) * 32768 + ldsc[r]);                      \
  }
#define STAGE_B(kt, rg)                                                   \
  {                                                                       \
    _Pragma("unroll") for (int r = 0; r < 2; ++r)                         \
        gload_lds16(srcB[r] + (size_t)(kt) * 64,                          \
                    lbase + (rg) * 32768 + 16384 + ldsc[r]);              \
  }
#define SUBITER(C0, C1, CBv, N0, N1, NBv, tcur)                           \
  {                                                                       \
    asm volatile("s_waitcnt vmcnt(4)" ::: "memory");                      \
    asm volatile("s_barrier" ::: "memory");                               \
    int tn = (tcur) + 1 < NT ? (tcur) + 1 : NT - 1;                       \
    const char* bA = lbase + (tn & 3) * 32768;                            \
    const char* bB = bA + 16384;                                          \
    _Pragma("unroll") for (int i = 0; i < 4; ++i)                         \
        NBv[i] = *(const s16x8*)(bB + boff + i * 1024);                   \
    _Pragma("unroll") for (int i = 0; i < 4; ++i)                         \
        N0[i] = *(const s16x8*)(bA + aoff + i * 1024);                    \
    _Pragma("unroll") for (int i = 0; i < 4; ++i)                         \
        N1[i] = *(const s16x8*)(bA + aoff + 4096 + i * 1024);             \
    int ts = (tcur) + 3 < NT ? (tcur) + 3 : NT - 1;                       \
    int rgs = ((tcur) + 3) & 3;                                           \
    STAGE_A(ts, rgs); STAGE_B(ts, rgs);                                   \
    __builtin_amdgcn_s_setprio(1);                                        \
    _Pragma("unroll") for (int mi = 0; mi < 4; ++mi)                      \
      _Pragma("unroll") for (int ni = 0; ni < 4; ++ni)                    \
          acc[mi][ni] = __builtin_amdgcn_mfma_f32_16x16x32_bf16(          \
              C0[mi], CBv[ni], acc[mi][ni], 0, 0, 0);                     \
    _Pragma("unroll") for (int mi = 0; mi < 4; ++mi)                      \
      _Pragma("unroll") for (int ni = 0; ni < 4; ++ni)                    \
          acc[mi + 4][ni] = __builtin_amdgcn_mfma_f32_16x16x32_bf16(      \
              C1[mi], CBv[ni], acc[mi + 4][ni], 0, 0, 0);                 \
    __builtin_amdgcn_s_setprio(0);                                        \
  }

  STAGE_A(0, 0); STAGE_B(0, 0);
  STAGE_A(1, 1); STAGE_B(1, 1);
  STAGE_A(2, 2); STAGE_B(2, 2);
  asm volatile("s_waitcnt vmcnt(8)" ::: "memory");
  asm volatile("s_barrier" ::: "memory");
  {
    const char* bA = lbase;
    const char* bB = bA + 16384;
#pragma unroll
    for (int i = 0; i < 4; ++i) cB[i]  = *(const s16x8*)(bB + boff + i * 1024);
#pragma unroll
    for (int i = 0; i < 4; ++i) cA0[i] = *(const s16x8*)(bA + aoff + i * 1024);
#pragma unroll
    for (int i = 0; i < 4; ++i)
      cA1[i] = *(const s16x8*)(bA + aoff + 4096 + i * 1024);
  }

  for (int t = 0; t < NT; t += 2) {
    SUBITER(cA0, cA1, cB, nA0, nA1, nB, t);
    SUBITER(nA0, nA1, nB, cA0, cA1, cB, t + 1);
  }
#undef SUBITER
#undef STAGE_A
#undef STAGE_B

  asm volatile("s_waitcnt vmcnt(0)" ::: "memory");

#pragma unroll
  for (int mi = 0; mi < 8; ++mi) {
#pragma unroll
    for (int ni = 0; ni < 4; ++ni) {
      int colg = n0 + wn * 64 + ni * 16 + (lane & 15);
      float badd = biasz[colg];
#pragma unroll
      for (int r = 0; r < 4; ++r) {
        int rowg = m0 + wm * 128 + mi * 16 + ((lane >> 4) << 2) + r;
        float v = acc[mi][ni][r] + badd;
        if constexpr (sizeof(OutT) == 2) Cg[(size_t)rowg * N + colg] = f2bf(v);
        else                             Cg[(size_t)rowg * N + colg] = v;
      }
    }
  }
}

// ---------------------------------------------------------------------------
// per-position head-mix attention, ALL 4 scales fused.
// ROLLED scale loop (register-safe form) + LDS K/V DOUBLE-BUFFER:
// DMA for scale s+1 issued into buf[(s+1)&1] under compute of scale s.
// Ledger/iter: [KV(s):4][q(s):2][KV(s+1):4] -> vmcnt(6) retires exactly
// KV(s); q's retire is compiler-counted. No cross-wave sharing -> no
// barriers; buffer reuse is structurally safe (wave issues KV(s+1) only
// after its own s-1 reads were consumed).
// 256 threads = 4 waves; wave = 1 position; lane = h*4 + dq.
// ---------------------------------------------------------------------------
__global__ __launch_bounds__(256) void k_attn_all(
    const u16* __restrict__ proj, u16* __restrict__ outbf,
    const float* __restrict__ sl, int rows) {
  __shared__ u16 kv[4][2][2][1024];   // [wave][buf][K/V][1024] = 32 KB
  int lane = threadIdx.x & 63, wid = threadIdx.x >> 6;
  int row = blockIdx.x * 4 + wid;
  int h = lane >> 2, dq = lane & 3;
  int doff = h * 64 + dq * 16;

  float l0 = sl[0], l1 = sl[1], l2 = sl[2], l3 = sl[3];
  float lm = fmaxf(fmaxf(l0, l1), fmaxf(l2, l3));
  float e0 = __expf(l0 - lm), e1 = __expf(l1 - lm), e2 = __expf(l2 - lm),
        e3 = __expf(l3 - lm);
  float esum = e0 + e1 + e2 + e3;
  float wsc4[4] = {e0 / esum, e1 / esum, e2 / esum, e3 / esum};

#define KV_ISSUE(s, buf)                                                   \
  {                                                                        \
    const u16* kr = proj + ((size_t)(3 * (s) + 1) * rows + row) * DDIM;    \
    const u16* vr = proj + ((size_t)(3 * (s) + 2) * rows + row) * DDIM;    \
    gload_lds16(kr + lane * 8,       &kv[wid][buf][0][0]);                 \
    gload_lds16(kr + 512 + lane * 8, &kv[wid][buf][0][512]);               \
    gload_lds16(vr + lane * 8,       &kv[wid][buf][1][0]);                 \
    gload_lds16(vr + 512 + lane * 8, &kv[wid][buf][1][512]);               \
  }

  KV_ISSUE(0, 0);   // prologue: scale 0 -> buf 0

  float acc[16];
#pragma unroll
  for (int i = 0; i < 16; ++i) acc[i] = 0.f;

  for (int s = 0; s < 4; ++s) {
    int buf = s & 1;

    // q slice for this lane (global->reg; compiler-counted retire)
    const u16* qr = proj + ((size_t)(3 * s) * rows + row) * DDIM + doff;
    u16x8 q0 = *reinterpret_cast<const u16x8*>(qr);
    u16x8 q1 = *reinterpret_cast<const u16x8*>(qr + 8);

    // prefetch next scale's K/V into the other buffer
    if (s < 3) KV_ISSUE(s + 1, buf ^ 1);

    // wait for KV(s) only (6 younger ops stay in flight); last iter drain
    if (s < 3) asm volatile("s_waitcnt vmcnt(6)" ::: "memory");
    else       asm volatile("s_waitcnt vmcnt(0)" ::: "memory");

    float qf[16];
#pragma unroll
    for (int i = 0; i < 8; ++i) {
      qf[i]     = b2f(q0[i]) * 0.125f;
      qf[8 + i] = b2f(q1[i]) * 0.125f;
    }

    float sc[16];
#pragma unroll
    for (int g = 0; g < 16; ++g) {
      const u16* kp = &kv[wid][buf][0][g * 64 + dq * 16];
      u16x8 k0 = *reinterpret_cast<const u16x8*>(kp);
      u16x8 k1 = *reinterpret_cast<const u16x8*>(kp + 8);
      float d = 0.f;
#pragma unroll
      for (int i = 0; i < 8; ++i) d = fmaf(qf[i], b2f(k0[i]), d);
#pragma unroll
      for (int i = 0; i < 8; ++i) d = fmaf(qf[8 + i], b2f(k1[i]), d);
      d += __shfl_xor(d, 1);
      d += __shfl_xor(d, 2);
      sc[g] = d;
    }

    float mx = sc[0];
#pragma unroll
    for (int g = 1; g < 16; ++g) mx = fmaxf(mx, sc[g]);
    float sum = 0.f;
#pragma unroll
    for (int g = 0; g < 16; ++g) { sc[g] = __expf(sc[g] - mx); sum += sc[g]; }
    float inv = wsc4[s] / sum;
#pragma unroll
    for (int g = 0; g < 16; ++g) sc[g] *= inv;

#pragma unroll
    for (int g = 0; g < 16; ++g) {
      float a = sc[g];
      const u16* vp = &kv[wid][buf][1][g * 64 + dq * 16];
      u16x8 v0 = *reinterpret_cast<const u16x8*>(vp);
      u16x8 v1 = *reinterpret_cast<const u16x8*>(vp + 8);
#pragma unroll
      for (int i = 0; i < 8; ++i) {
        acc[i]     = fmaf(a, b2f(v0[i]), acc[i]);
        acc[8 + i] = fmaf(a, b2f(v1[i]), acc[8 + i]);
      }
    }
  }
#undef KV_ISSUE

  u16* op = outbf + (size_t)row * DDIM + doff;
  u16x8 o0, o1;
#pragma unroll
  for (int i = 0; i < 8; ++i) {
    o0[i] = f2bf(acc[i]);
    o1[i] = f2bf(acc[8 + i]);
  }
  *reinterpret_cast<u16x8*>(op) = o0;
  *reinterpret_cast<u16x8*>(op + 8) = o1;
}

// ---------------------------------------------------------------------------
extern "C" void kernel_launch(void* const* d_in, const int* in_sizes, int n_in,
                              void* d_out, int out_size, void* d_ws,
                              size_t ws_size, hipStream_t stream) {
  const float* x  = (const float*)d_in[0];
  const float* sl = (const float*)d_in[1];
  const float* wq = (const float*)d_in[2];
  const float* bq = (const float*)d_in[3];
  const float* wk = (const float*)d_in[4];
  const float* bk = (const float*)d_in[5];
  const float* wv = (const float*)d_in[6];
  const float* bv = (const float*)d_in[7];
  const float* wo = (const float*)d_in[8];
  const float* bo = (const float*)d_in[9];
  const float* ws = (const float*)d_in[10];
  const float* bs = (const float*)d_in[11];
  float* out = (float*)d_out;

  char* wsb = (char*)d_ws;
  size_t off = 0;
  u16* xbf    = (u16*)(wsb + off); off += (size_t)MM * DDIM * 2;   // 32 MB
  u16* wfus   = (u16*)(wsb + off); off += 12ull * DDSQ * 2;        // 24 MB
  u16* wobf   = (u16*)(wsb + off); off += DDSQ * 2;                // 2 MB
  float* bfus = (float*)(wsb + off); off += 65536;                 // 48 KB + pad
  u16* combc  = (u16*)(wsb + off); off += (size_t)MM * DDIM * 2;   // 32 MB
  char* dynr  = wsb + off;
  size_t fixed = off;

  int chunk = 4096;
  while (chunk > 1024 && fixed + (size_t)12 * chunk * DDIM * 2 > ws_size)
    chunk >>= 1;
  u16* projc = (u16*)dynr;
  u16* wtT  = (u16*)dynr;                      // prefuse overlay, 6 MB
  u16* wsbf = (u16*)(dynr + 3ull * DDSQ * 2);  // prefuse overlay, 8 MB

  int n4;
  n4 = MM * DDIM / 4;
  k_f32_to_bf16<<<(n4 + 255) / 256, 256, 0, stream>>>(x, xbf, n4);
  n4 = (int)(4 * DDSQ / 4);
  k_f32_to_bf16<<<(n4 + 255) / 256, 256, 0, stream>>>(ws, wsbf, n4);
  n4 = (int)(DDSQ / 4);
  k_f32_to_bf16<<<(n4 + 255) / 256, 256, 0, stream>>>(wo, wobf, n4);

  k_transpose_bf16<<<dim3(32, 32, 3), dim3(32, 8), 0, stream>>>(wq, wk, wv, wtT);
  k_bias_fuse<<<dim3(256, 12), 256, 0, stream>>>(ws, bq, bk, bv, bs, bfus);

  // fused weights (m97 kernel, known good)
  k_gemm_bt<u16><<<dim3(96, 8), 256, 0, stream>>>(
      wsbf, wtT, wfus, nullptr, 1024, 1024, 1024, DDSQ, DDSQ, DDSQ, 0, 1);

  // chunked: proj (12 batched, round-7 256^2 GEMM) -> fused attention
  int nchunks = MM / chunk;
  for (int c = 0; c < nchunks; ++c) {
    const u16* xa = xbf + (size_t)c * chunk * DDIM;
    k_gemm256<u16><<<dim3(48, chunk / 256), 512, 0, stream>>>(
        xa, wfus, projc, bfus, chunk, 1024, 1024,
        0, DDSQ, (size_t)chunk * DDIM, DDIM, 4);
    k_attn_all<<<dim3(chunk / 4), 256, 0, stream>>>(
        projc, combc + (size_t)c * chunk * DDIM, sl, chunk);
  }

  // single final GEMM (round-7 kernel): out = comb_bf @ wo^T + bo
  k_gemm256<float><<<dim3(4, 64), 512, 0, stream>>>(
      combc, wobf, out, bo, MM, 1024, 1024, 0, 0, 0, 0, 4);
}